// Round 1
// baseline (2603.736 us; speedup 1.0000x reference)
//
#include <hip/hip_runtime.h>

constexpr int NN  = 50000;
constexpr int NE  = 800000;
constexpr int DIN = 256;
constexpr int HH  = 256;
constexpr int NL  = 4;
constexpr float EPS = 1e-5f;

// ---------------- CSR build (by dst) ----------------

__global__ void k_hist(const int* __restrict__ ei, int* __restrict__ deg) {
    int e = blockIdx.x * 256 + threadIdx.x;
    if (e < NE) atomicAdd(&deg[ei[NE + e]], 1);
}

__global__ __launch_bounds__(1024) void k_scan(const int* __restrict__ deg,
                                               int* __restrict__ row_start,
                                               int* __restrict__ cursor,
                                               float* __restrict__ inv_deg) {
    __shared__ int part[1024];
    const int t = threadIdx.x;
    const int C = (NN + 1023) / 1024;
    const int base = t * C;
    int local = 0;
    for (int i = 0; i < C; ++i) { int idx = base + i; if (idx < NN) local += deg[idx]; }
    part[t] = local;
    __syncthreads();
    for (int off = 1; off < 1024; off <<= 1) {
        int add = (t >= off) ? part[t - off] : 0;
        __syncthreads();
        part[t] += add;
        __syncthreads();
    }
    int run = (t == 0) ? 0 : part[t - 1];
    for (int i = 0; i < C; ++i) {
        int idx = base + i;
        if (idx < NN) {
            int d = deg[idx];
            row_start[idx] = run;
            cursor[idx] = run;
            inv_deg[idx] = 1.0f / (float)max(d, 1);
            run += d;
        }
    }
    if (t == 0) row_start[NN] = part[1023];
}

__global__ void k_fill(const int* __restrict__ ei, int* __restrict__ cursor,
                       int* __restrict__ col) {
    int e = blockIdx.x * 256 + threadIdx.x;
    if (e >= NE) return;
    int s = ei[e], d = ei[NE + e];
    int pos = atomicAdd(&cursor[d], 1);
    col[pos] = s;
}

// ---------------- mean aggregation: one wave per node ----------------

__global__ __launch_bounds__(256) void k_aggregate(const float* __restrict__ h,
                                                   const int* __restrict__ row_start,
                                                   const int* __restrict__ col,
                                                   const float* __restrict__ inv_deg,
                                                   float* __restrict__ agg) {
    const int node = blockIdx.x * 4 + (threadIdx.x >> 6);
    const int lane = threadIdx.x & 63;
    if (node >= NN) return;
    const int s = row_start[node], e = row_start[node + 1];
    float4 acc = {0.f, 0.f, 0.f, 0.f};
    int p = s;
    for (; p + 1 < e; p += 2) {
        int c0 = col[p], c1 = col[p + 1];
        float4 a = *(const float4*)&h[(size_t)c0 * HH + lane * 4];
        float4 b = *(const float4*)&h[(size_t)c1 * HH + lane * 4];
        acc.x += a.x + b.x; acc.y += a.y + b.y;
        acc.z += a.z + b.z; acc.w += a.w + b.w;
    }
    if (p < e) {
        int c0 = col[p];
        float4 a = *(const float4*)&h[(size_t)c0 * HH + lane * 4];
        acc.x += a.x; acc.y += a.y; acc.z += a.z; acc.w += a.w;
    }
    const float g = inv_deg[node];
    float4 o = {acc.x * g, acc.y * g, acc.z * g, acc.w * g};
    *(float4*)&agg[(size_t)node * HH + lane * 4] = o;
}

// ---------------- f32 NT GEMM: C[m,j] = sum_k A[m,k]*W[j,k] (+bias)(+C)(+relu(BN(D)))(+relu) ----
// 128x128 block tile, 8x8 micro tile, BK=16. LDS transposed tiles, stride 136
// floats -> all LDS access <=2-way bank conflict (free).

template<bool ACCUM, bool RELU, bool BNADD>
__global__ __launch_bounds__(256) void k_gemm_nt(
    int M, int K, int J,
    const float* __restrict__ A, const float* __restrict__ W,
    const float* __restrict__ bias,
    const float* __restrict__ D, const float* __restrict__ scsh,
    float* __restrict__ C)
{
    __shared__ float As[16][136];
    __shared__ float Ws[16][136];
    const int tid = threadIdx.x;
    const int tx = tid & 15;       // j micro index
    const int ty = tid >> 4;       // m micro index
    const int m0 = blockIdx.x * 128;
    const int j0 = blockIdx.y * 128;
    const int lr = tid >> 1;       // 0..127 (tile row for loads)
    const int lq = (tid & 1) * 8;  // 0 or 8 (k offset for loads)
    float acc[8][8] = {};

    for (int k0 = 0; k0 < K; k0 += 16) {
        float4 a0 = {0,0,0,0}, a1 = {0,0,0,0};
        const int arow = m0 + lr;
        if (arow < M) {
            const float* ap = &A[(size_t)arow * K + k0 + lq];
            a0 = *(const float4*)(ap);
            a1 = *(const float4*)(ap + 4);
        }
        const float* wp = &W[(size_t)(j0 + lr) * K + k0 + lq];
        const float4 w0 = *(const float4*)(wp);
        const float4 w1 = *(const float4*)(wp + 4);
        __syncthreads();
        {
            const float av[8] = {a0.x,a0.y,a0.z,a0.w,a1.x,a1.y,a1.z,a1.w};
            const float wv[8] = {w0.x,w0.y,w0.z,w0.w,w1.x,w1.y,w1.z,w1.w};
            #pragma unroll
            for (int i = 0; i < 8; ++i) {
                As[lq + i][lr] = av[i];
                Ws[lq + i][lr] = wv[i];
            }
        }
        __syncthreads();
        #pragma unroll
        for (int kk = 0; kk < 16; ++kk) {
            const float4 A0 = *(const float4*)&As[kk][ty * 8];
            const float4 A1 = *(const float4*)&As[kk][ty * 8 + 4];
            const float4 B0 = *(const float4*)&Ws[kk][tx * 4];
            const float4 B1 = *(const float4*)&Ws[kk][64 + tx * 4];
            const float ar[8] = {A0.x,A0.y,A0.z,A0.w,A1.x,A1.y,A1.z,A1.w};
            const float br[8] = {B0.x,B0.y,B0.z,B0.w,B1.x,B1.y,B1.z,B1.w};
            #pragma unroll
            for (int mi = 0; mi < 8; ++mi)
                #pragma unroll
                for (int ji = 0; ji < 8; ++ji)
                    acc[mi][ji] = fmaf(ar[mi], br[ji], acc[mi][ji]);
        }
    }

    #pragma unroll
    for (int mi = 0; mi < 8; ++mi) {
        const int row = m0 + ty * 8 + mi;
        if (row >= M) continue;
        #pragma unroll
        for (int g = 0; g < 2; ++g) {
            const int jc = j0 + g * 64 + tx * 4;
            const size_t cb = (size_t)row * J + jc;
            float v[4];
            #pragma unroll
            for (int ji = 0; ji < 4; ++ji) v[ji] = acc[mi][g * 4 + ji];
            if (bias) {
                #pragma unroll
                for (int ji = 0; ji < 4; ++ji) v[ji] += bias[jc + ji];
            }
            if (ACCUM) {
                const float4 o = *(const float4*)&C[cb];
                v[0] += o.x; v[1] += o.y; v[2] += o.z; v[3] += o.w;
            }
            if (BNADD) {
                const float4 d4 = *(const float4*)&D[cb];
                const float dr[4] = {d4.x, d4.y, d4.z, d4.w};
                #pragma unroll
                for (int ji = 0; ji < 4; ++ji) {
                    const float bn = dr[ji] * scsh[jc + ji] + scsh[HH + jc + ji];
                    v[ji] += fmaxf(bn, 0.0f);
                }
            }
            if (RELU) {
                #pragma unroll
                for (int ji = 0; ji < 4; ++ji) v[ji] = fmaxf(v[ji], 0.0f);
            }
            const float4 vo = {v[0], v[1], v[2], v[3]};
            *(float4*)&C[cb] = vo;
        }
    }
}

// ---------------- BatchNorm stats ----------------

__global__ __launch_bounds__(256) void k_bn_stats(const float* __restrict__ X,
                                                  float* __restrict__ stats) {
    const int colj = threadIdx.x;
    const int RPB = (NN + gridDim.x - 1) / gridDim.x;
    const int r0 = blockIdx.x * RPB;
    const int r1 = min(r0 + RPB, NN);
    float s = 0.f, ss = 0.f;
    for (int r = r0; r < r1; ++r) {
        float v = X[(size_t)r * HH + colj];
        s += v;
        ss = fmaf(v, v, ss);
    }
    atomicAdd(&stats[colj], s);
    atomicAdd(&stats[HH + colj], ss);
}

__global__ void k_bn_finalize(const float* __restrict__ stats,
                              const float* __restrict__ g,
                              const float* __restrict__ b,
                              float* __restrict__ scsh) {
    const int j = threadIdx.x;
    const float inv_n = 1.0f / (float)NN;
    const float mu = stats[j] * inv_n;
    const float var = stats[HH + j] * inv_n - mu * mu;
    const float rstd = rsqrtf(var + EPS);
    const float sc = g[j] * rstd;
    scsh[j] = sc;
    scsh[HH + j] = b[j] - mu * sc;
}

// ---------------- out proj (DOUT=2) + log_softmax: one wave per row ----------------

__global__ __launch_bounds__(256) void k_out(const float* __restrict__ h,
                                             const float* __restrict__ ow,
                                             const float* __restrict__ ob,
                                             float* __restrict__ out) {
    const int row = blockIdx.x * 4 + (threadIdx.x >> 6);
    const int lane = threadIdx.x & 63;
    if (row >= NN) return;
    const float4 hv = *(const float4*)&h[(size_t)row * HH + lane * 4];
    const float4 w0 = *(const float4*)&ow[lane * 4];
    const float4 w1 = *(const float4*)&ow[HH + lane * 4];
    float p0 = hv.x * w0.x + hv.y * w0.y + hv.z * w0.z + hv.w * w0.w;
    float p1 = hv.x * w1.x + hv.y * w1.y + hv.z * w1.z + hv.w * w1.w;
    #pragma unroll
    for (int off = 32; off >= 1; off >>= 1) {
        p0 += __shfl_down(p0, off);
        p1 += __shfl_down(p1, off);
    }
    if (lane == 0) {
        p0 += ob[0]; p1 += ob[1];
        const float m = fmaxf(p0, p1);
        const float lse = m + logf(__expf(p0 - m) + __expf(p1 - m));
        out[(size_t)row * 2 + 0] = p0 - lse;
        out[(size_t)row * 2 + 1] = p1 - lse;
    }
}

// ---------------- host ----------------

template<bool ACCUM, bool RELU, bool BNADD>
static void launch_gemm(int M, int K, int J, const float* A, const float* W,
                        const float* bias, const float* D, const float* scsh,
                        float* C, hipStream_t stream) {
    dim3 grid((M + 127) / 128, J / 128);
    k_gemm_nt<ACCUM, RELU, BNADD><<<grid, 256, 0, stream>>>(M, K, J, A, W, bias, D, scsh, C);
}

extern "C" void kernel_launch(void* const* d_in, const int* in_sizes, int n_in,
                              void* d_out, int out_size, void* d_ws, size_t ws_size,
                              hipStream_t stream) {
    const float* x       = (const float*)d_in[0];
    const int*   ei      = (const int*)d_in[1];
    const float* in_w    = (const float*)d_in[2];
    const float* in_b    = (const float*)d_in[3];
    const float* conv_wl = (const float*)d_in[4];
    const float* conv_bl = (const float*)d_in[5];
    const float* conv_wr = (const float*)d_in[6];
    const float* bn_g    = (const float*)d_in[7];
    const float* bn_b    = (const float*)d_in[8];
    const float* skip_w  = (const float*)d_in[9];
    const float* skip_b  = (const float*)d_in[10];
    const float* mlp_w1  = (const float*)d_in[11];
    const float* mlp_b1  = (const float*)d_in[12];
    const float* mlp_w2  = (const float*)d_in[13];
    const float* mlp_b2  = (const float*)d_in[14];
    const float* out_w   = (const float*)d_in[15];
    const float* out_b   = (const float*)d_in[16];
    float* out = (float*)d_out;
    (void)in_sizes; (void)n_in; (void)out_size; (void)ws_size;

    char* base = (char*)d_ws;
    size_t off = 0;
    auto alloc = [&](size_t bytes) -> void* {
        void* p = base + off;
        off += (bytes + 255) & ~(size_t)255;
        return p;
    };
    int*   deg   = (int*)alloc((size_t)NN * sizeof(int));
    int*   rs    = (int*)alloc((size_t)(NN + 1) * sizeof(int));
    int*   cur   = (int*)alloc((size_t)NN * sizeof(int));
    int*   col   = (int*)alloc((size_t)NE * sizeof(int));
    float* idg   = (float*)alloc((size_t)NN * sizeof(float));
    float* stats = (float*)alloc(2 * HH * sizeof(float));
    float* scsh  = (float*)alloc(2 * HH * sizeof(float));
    float* P0    = (float*)alloc((size_t)NN * HH * sizeof(float));
    float* P1    = (float*)alloc((size_t)NN * HH * sizeof(float));
    float* P2    = (float*)alloc((size_t)NN * HH * sizeof(float));  // P1,P2 contiguous

    // CSR build
    hipMemsetAsync(deg, 0, (size_t)NN * sizeof(int), stream);
    k_hist<<<(NE + 255) / 256, 256, 0, stream>>>(ei, deg);
    k_scan<<<1, 1024, 0, stream>>>(deg, rs, cur, idg);
    k_fill<<<(NE + 255) / 256, 256, 0, stream>>>(ei, cur, col);

    // input projection + ReLU
    launch_gemm<false, true, false>(NN, DIN, HH, x, in_w, in_b, nullptr, nullptr, P0, stream);

    float* hcur = P0;
    float* hbuf = P1;
    float* conv = P2;
    for (int l = 0; l < NL; ++l) {
        k_aggregate<<<(NN + 3) / 4, 256, 0, stream>>>(hcur, rs, col, idg, hbuf);
        launch_gemm<false, false, false>(NN, HH, HH, hbuf, conv_wl + (size_t)l * HH * HH,
                                         conv_bl + l * HH, nullptr, nullptr, conv, stream);
        launch_gemm<true, false, false>(NN, HH, HH, hcur, conv_wr + (size_t)l * HH * HH,
                                        nullptr, nullptr, nullptr, conv, stream);
        hipMemsetAsync(stats, 0, 2 * HH * sizeof(float), stream);
        k_bn_stats<<<256, 256, 0, stream>>>(conv, stats);
        k_bn_finalize<<<1, 256, 0, stream>>>(stats, bn_g + l * HH, bn_b + l * HH, scsh);
        // h_next = relu(BN(conv)) + hcur @ skip_w^T + skip_b   (written into hbuf)
        launch_gemm<false, false, true>(NN, HH, HH, hcur, skip_w + (size_t)l * HH * HH,
                                        skip_b + l * HH, conv, scsh, hbuf, stream);
        float* t = hcur; hcur = hbuf; hbuf = t;
    }
    // after 4 swaps hcur == P0; P1,P2 free and contiguous -> MLP hidden (NN x 512)
    float* mid = P1;
    launch_gemm<false, true, false>(NN, HH, 2 * HH, hcur, mlp_w1, mlp_b1, nullptr, nullptr, mid, stream);
    launch_gemm<false, false, false>(NN, 2 * HH, HH, mid, mlp_w2, mlp_b2, nullptr, nullptr, hcur, stream);

    k_out<<<(NN + 3) / 4, 256, 0, stream>>>(hcur, out_w, out_b, out);
}

// Round 2
// 1494.354 us; speedup vs baseline: 1.7424x; 1.7424x over previous
//
#include <hip/hip_runtime.h>

using u16 = unsigned short;
using u32 = unsigned int;
typedef __attribute__((ext_vector_type(8))) short bf16x8;   // 8 bf16 in 4 VGPRs
typedef __attribute__((ext_vector_type(4))) float f32x4;

constexpr int NN  = 50000;
constexpr int NE  = 800000;
constexpr int DIN = 256;
constexpr int HH  = 256;
constexpr int NL  = 4;
constexpr float EPS = 1e-5f;

// ---- f32 -> bf16 hi/lo split (compensated representation, ~2^-17 rel) ----
__device__ __forceinline__ void split2(float v, u16& h, u16& l) {
    u32 u  = __float_as_uint(v);
    u32 hu = (u + 0x8000u) >> 16;            // round-half-up to bf16
    float hf = __uint_as_float(hu << 16);
    float d  = v - hf;                        // exact residual
    u32 du = __float_as_uint(d);
    u32 lu = (du + 0x8000u) >> 16;
    h = (u16)hu; l = (u16)lu;
}

__global__ void k_split(const float* __restrict__ src, u16* __restrict__ hi,
                        u16* __restrict__ lo, int n) {
    int i = blockIdx.x * 256 + threadIdx.x;
    if (i < n) { u16 h, l; split2(src[i], h, l); hi[i] = h; lo[i] = l; }
}

// ---------------- CSR build (by dst) ----------------

__global__ void k_hist(const int* __restrict__ ei, int* __restrict__ deg) {
    int e = blockIdx.x * 256 + threadIdx.x;
    if (e < NE) atomicAdd(&deg[ei[NE + e]], 1);
}

__global__ __launch_bounds__(1024) void k_scan(const int* __restrict__ deg,
                                               int* __restrict__ row_start,
                                               int* __restrict__ cursor,
                                               float* __restrict__ inv_deg) {
    __shared__ int part[1024];
    const int t = threadIdx.x;
    const int C = (NN + 1023) / 1024;
    const int base = t * C;
    int local = 0;
    for (int i = 0; i < C; ++i) { int idx = base + i; if (idx < NN) local += deg[idx]; }
    part[t] = local;
    __syncthreads();
    for (int off = 1; off < 1024; off <<= 1) {
        int add = (t >= off) ? part[t - off] : 0;
        __syncthreads();
        part[t] += add;
        __syncthreads();
    }
    int run = (t == 0) ? 0 : part[t - 1];
    for (int i = 0; i < C; ++i) {
        int idx = base + i;
        if (idx < NN) {
            int d = deg[idx];
            row_start[idx] = run;
            cursor[idx] = run;
            inv_deg[idx] = 1.0f / (float)max(d, 1);
            run += d;
        }
    }
    if (t == 0) row_start[NN] = part[1023];
}

__global__ void k_fill(const int* __restrict__ ei, int* __restrict__ cursor,
                       int* __restrict__ col) {
    int e = blockIdx.x * 256 + threadIdx.x;
    if (e >= NE) return;
    int s = ei[e], d = ei[NE + e];
    int pos = atomicAdd(&cursor[d], 1);
    col[pos] = s;
}

// ---------------- mean aggregation: one wave per node ----------------

__global__ __launch_bounds__(256) void k_aggregate(const float* __restrict__ h,
                                                   const int* __restrict__ row_start,
                                                   const int* __restrict__ col,
                                                   const float* __restrict__ inv_deg,
                                                   float* __restrict__ agg) {
    const int node = blockIdx.x * 4 + (threadIdx.x >> 6);
    const int lane = threadIdx.x & 63;
    if (node >= NN) return;
    const int s = row_start[node], e = row_start[node + 1];
    float4 acc = {0.f, 0.f, 0.f, 0.f};
    int p = s;
    for (; p + 1 < e; p += 2) {
        int c0 = col[p], c1 = col[p + 1];
        float4 a = *(const float4*)&h[(size_t)c0 * HH + lane * 4];
        float4 b = *(const float4*)&h[(size_t)c1 * HH + lane * 4];
        acc.x += a.x + b.x; acc.y += a.y + b.y;
        acc.z += a.z + b.z; acc.w += a.w + b.w;
    }
    if (p < e) {
        int c0 = col[p];
        float4 a = *(const float4*)&h[(size_t)c0 * HH + lane * 4];
        acc.x += a.x; acc.y += a.y; acc.z += a.z; acc.w += a.w;
    }
    const float g = inv_deg[node];
    float4 o = {acc.x * g, acc.y * g, acc.z * g, acc.w * g};
    *(float4*)&agg[(size_t)node * HH + lane * 4] = o;
}

// ---------------- compensated bf16 MFMA GEMM ----------------
// C[m,j] = sum_k A[m,k] * W[j,k]  (+bias) (+relu(BN(D)) for BNADD) (+relu)
// A: f32, split hi/lo in-register during staging. W: pre-split bf16 planes.
// K may span two sources: k<256 -> (A0,Wh0,Wl0), k>=256 -> (A1,Wh1,Wl1).
// 128x128 tile, BK=32, 4 waves (2x2), each wave 64x64 via 4x4 16x16x32 frags.
// acc += Ah*Wh + Ah*Wl + Al*Wh   (compensated product)

template<bool RELU, bool BNADD>
__global__ __launch_bounds__(256, 2) void k_gemm_mfma(
    int M, int K, int J, int lda, int ldw,
    const float* __restrict__ A0, const float* __restrict__ A1,
    const u16* __restrict__ Wh0, const u16* __restrict__ Wl0,
    const u16* __restrict__ Wh1, const u16* __restrict__ Wl1,
    const float* __restrict__ bias,
    const float* __restrict__ D, const float* __restrict__ scsh,
    float* __restrict__ C)
{
    __shared__ u16 Ah[128 * 32];
    __shared__ u16 Al[128 * 32];
    __shared__ u16 Bh[128 * 32];
    __shared__ u16 Bl[128 * 32];

    const int tid  = threadIdx.x;
    const int w    = tid >> 6;
    const int lane = tid & 63;
    const int m0 = blockIdx.x * 128;
    const int j0 = blockIdx.y * 128;
    const int wm = w >> 1, wn = w & 1;
    const int lr = lane & 15, lk = lane >> 4;

    // A staging role: thread covers row ar, k cols ak..ak+15 (f32)
    const int ar = tid >> 1;
    const int ak = (tid & 1) * 16;
    const int arow = m0 + ar;

    f32x4 zero4 = {0.f, 0.f, 0.f, 0.f};
    f32x4 acc[4][4];
    #pragma unroll
    for (int mi = 0; mi < 4; ++mi)
        #pragma unroll
        for (int ni = 0; ni < 4; ++ni) acc[mi][ni] = zero4;

    for (int k0 = 0; k0 < K; k0 += 32) {
        // ---- issue A global loads (f32) ----
        const float* As = (k0 < 256) ? A0 : A1;
        const int kc = k0 & 255;
        float4 av[4];
        if (arow < M) {
            const float* ap = As + (size_t)arow * lda + kc + ak;
            av[0] = *(const float4*)(ap);
            av[1] = *(const float4*)(ap + 4);
            av[2] = *(const float4*)(ap + 8);
            av[3] = *(const float4*)(ap + 12);
        } else {
            av[0] = av[1] = av[2] = av[3] = float4{0.f, 0.f, 0.f, 0.f};
        }

        __syncthreads();   // all waves done reading previous tile

        // ---- convert A to hi/lo and ds_write ----
        {
            const float* vf = (const float*)av;
            u32 hp[8], lp[8];
            #pragma unroll
            for (int i = 0; i < 8; ++i) {
                u16 h0, l0, h1, l1;
                split2(vf[2 * i], h0, l0);
                split2(vf[2 * i + 1], h1, l1);
                hp[i] = (u32)h0 | ((u32)h1 << 16);
                lp[i] = (u32)l0 | ((u32)l1 << 16);
            }
            uint4* dh = (uint4*)&Ah[ar * 32 + ak];
            uint4* dl = (uint4*)&Al[ar * 32 + ak];
            dh[0] = uint4{hp[0], hp[1], hp[2], hp[3]};
            dh[1] = uint4{hp[4], hp[5], hp[6], hp[7]};
            dl[0] = uint4{lp[0], lp[1], lp[2], lp[3]};
            dl[1] = uint4{lp[4], lp[5], lp[6], lp[7]};
        }

        // ---- B staging: global_load_lds direct from bf16 planes ----
        {
            const u16* Whs = (k0 < 256) ? Wh0 : Wh1;
            const u16* Wls = (k0 < 256) ? Wl0 : Wl1;
            #pragma unroll
            for (int i = 0; i < 2; ++i) {
                const int c = w + i * 4;                    // chunk 0..7 = rows 16c..16c+15
                const int r = 16 * c + (lane >> 2);
                const size_t goff = (size_t)(j0 + r) * ldw + kc + (lane & 3) * 8;
                __builtin_amdgcn_global_load_lds(
                    (const __attribute__((address_space(1))) void*)(Whs + goff),
                    (__attribute__((address_space(3))) void*)&Bh[c * 512], 16, 0, 0);
                __builtin_amdgcn_global_load_lds(
                    (const __attribute__((address_space(1))) void*)(Wls + goff),
                    (__attribute__((address_space(3))) void*)&Bl[c * 512], 16, 0, 0);
            }
        }

        __syncthreads();   // LDS tiles ready (vmcnt+lgkmcnt drained by barrier)

        // ---- fragment reads + MFMA ----
        bf16x8 af[4][2], bfr[4][2];
        #pragma unroll
        for (int mi = 0; mi < 4; ++mi) {
            const int off = (wm * 64 + mi * 16 + lr) * 32 + lk * 8;
            af[mi][0] = *(const bf16x8*)&Ah[off];
            af[mi][1] = *(const bf16x8*)&Al[off];
        }
        #pragma unroll
        for (int ni = 0; ni < 4; ++ni) {
            const int off = (wn * 64 + ni * 16 + lr) * 32 + lk * 8;
            bfr[ni][0] = *(const bf16x8*)&Bh[off];
            bfr[ni][1] = *(const bf16x8*)&Bl[off];
        }
        #pragma unroll
        for (int mi = 0; mi < 4; ++mi)
            #pragma unroll
            for (int ni = 0; ni < 4; ++ni) {
                acc[mi][ni] = __builtin_amdgcn_mfma_f32_16x16x32_bf16(
                    af[mi][0], bfr[ni][0], acc[mi][ni], 0, 0, 0);
                acc[mi][ni] = __builtin_amdgcn_mfma_f32_16x16x32_bf16(
                    af[mi][0], bfr[ni][1], acc[mi][ni], 0, 0, 0);
                acc[mi][ni] = __builtin_amdgcn_mfma_f32_16x16x32_bf16(
                    af[mi][1], bfr[ni][0], acc[mi][ni], 0, 0, 0);
            }
    }

    // ---- epilogue: C/D frag layout col=lane&15, row=(lane>>4)*4+r ----
    #pragma unroll
    for (int mi = 0; mi < 4; ++mi) {
        #pragma unroll
        for (int ni = 0; ni < 4; ++ni) {
            const int colj = j0 + wn * 64 + ni * 16 + lr;
            const float bv = bias[colj];
            float sc = 0.f, sh = 0.f;
            if (BNADD) { sc = scsh[colj]; sh = scsh[HH + colj]; }
            #pragma unroll
            for (int r = 0; r < 4; ++r) {
                const int row = m0 + wm * 64 + mi * 16 + lk * 4 + r;
                if (row >= M) continue;
                float v = acc[mi][ni][r] + bv;
                if (BNADD) {
                    const float dv = D[(size_t)row * J + colj];
                    v += fmaxf(dv * sc + sh, 0.f);
                }
                if (RELU) v = fmaxf(v, 0.f);
                C[(size_t)row * J + colj] = v;
            }
        }
    }
}

// ---------------- BatchNorm stats ----------------

__global__ __launch_bounds__(256) void k_bn_stats(const float* __restrict__ X,
                                                  float* __restrict__ stats) {
    const int colj = threadIdx.x;
    const int RPB = (NN + gridDim.x - 1) / gridDim.x;
    const int r0 = blockIdx.x * RPB;
    const int r1 = min(r0 + RPB, NN);
    float s = 0.f, ss = 0.f;
    for (int r = r0; r < r1; ++r) {
        float v = X[(size_t)r * HH + colj];
        s += v;
        ss = fmaf(v, v, ss);
    }
    atomicAdd(&stats[colj], s);
    atomicAdd(&stats[HH + colj], ss);
}

__global__ void k_bn_finalize(const float* __restrict__ stats,
                              const float* __restrict__ g,
                              const float* __restrict__ b,
                              float* __restrict__ scsh) {
    const int j = threadIdx.x;
    const float inv_n = 1.0f / (float)NN;
    const float mu = stats[j] * inv_n;
    const float var = stats[HH + j] * inv_n - mu * mu;
    const float rstd = rsqrtf(var + EPS);
    const float sc = g[j] * rstd;
    scsh[j] = sc;
    scsh[HH + j] = b[j] - mu * sc;
}

// ---------------- out proj (DOUT=2) + log_softmax ----------------

__global__ __launch_bounds__(256) void k_out(const float* __restrict__ h,
                                             const float* __restrict__ ow,
                                             const float* __restrict__ ob,
                                             float* __restrict__ out) {
    const int row = blockIdx.x * 4 + (threadIdx.x >> 6);
    const int lane = threadIdx.x & 63;
    if (row >= NN) return;
    const float4 hv = *(const float4*)&h[(size_t)row * HH + lane * 4];
    const float4 w0 = *(const float4*)&ow[lane * 4];
    const float4 w1 = *(const float4*)&ow[HH + lane * 4];
    float p0 = hv.x * w0.x + hv.y * w0.y + hv.z * w0.z + hv.w * w0.w;
    float p1 = hv.x * w1.x + hv.y * w1.y + hv.z * w1.z + hv.w * w1.w;
    #pragma unroll
    for (int off = 32; off >= 1; off >>= 1) {
        p0 += __shfl_down(p0, off);
        p1 += __shfl_down(p1, off);
    }
    if (lane == 0) {
        p0 += ob[0]; p1 += ob[1];
        const float m = fmaxf(p0, p1);
        const float lse = m + logf(__expf(p0 - m) + __expf(p1 - m));
        out[(size_t)row * 2 + 0] = p0 - lse;
        out[(size_t)row * 2 + 1] = p1 - lse;
    }
}

// ---------------- host ----------------

template<bool RELU, bool BNADD>
static void launch_mfma(int M, int K, int J, int lda, int ldw,
                        const float* A0, const float* A1,
                        const u16* Wh0, const u16* Wl0,
                        const u16* Wh1, const u16* Wl1,
                        const float* bias, const float* D, const float* scsh,
                        float* C, hipStream_t stream) {
    dim3 grid((M + 127) / 128, J / 128);
    k_gemm_mfma<RELU, BNADD><<<grid, 256, 0, stream>>>(
        M, K, J, lda, ldw, A0, A1, Wh0, Wl0, Wh1, Wl1, bias, D, scsh, C);
}

extern "C" void kernel_launch(void* const* d_in, const int* in_sizes, int n_in,
                              void* d_out, int out_size, void* d_ws, size_t ws_size,
                              hipStream_t stream) {
    const float* x       = (const float*)d_in[0];
    const int*   ei      = (const int*)d_in[1];
    const float* in_w    = (const float*)d_in[2];
    const float* in_b    = (const float*)d_in[3];
    const float* conv_wl = (const float*)d_in[4];
    const float* conv_bl = (const float*)d_in[5];
    const float* conv_wr = (const float*)d_in[6];
    const float* bn_g    = (const float*)d_in[7];
    const float* bn_b    = (const float*)d_in[8];
    const float* skip_w  = (const float*)d_in[9];
    const float* skip_b  = (const float*)d_in[10];
    const float* mlp_w1  = (const float*)d_in[11];
    const float* mlp_b1  = (const float*)d_in[12];
    const float* mlp_w2  = (const float*)d_in[13];
    const float* mlp_b2  = (const float*)d_in[14];
    const float* out_w   = (const float*)d_in[15];
    const float* out_b   = (const float*)d_in[16];
    float* out = (float*)d_out;
    (void)in_sizes; (void)n_in; (void)out_size; (void)ws_size;

    char* base = (char*)d_ws;
    size_t off = 0;
    auto alloc = [&](size_t bytes) -> void* {
        void* p = base + off;
        off += (bytes + 255) & ~(size_t)255;
        return p;
    };
    int*   deg   = (int*)alloc((size_t)NN * sizeof(int));
    int*   rs    = (int*)alloc((size_t)(NN + 1) * sizeof(int));
    int*   cur   = (int*)alloc((size_t)NN * sizeof(int));
    int*   col   = (int*)alloc((size_t)NE * sizeof(int));
    float* idg   = (float*)alloc((size_t)NN * sizeof(float));
    float* stats = (float*)alloc(2 * HH * sizeof(float));
    float* scsh  = (float*)alloc(2 * HH * sizeof(float));
    // bf16 weight planes (hi/lo)
    u16* win_h = (u16*)alloc(65536 * sizeof(u16));
    u16* win_l = (u16*)alloc(65536 * sizeof(u16));
    u16* wl_h  = (u16*)alloc(4 * 65536 * sizeof(u16));
    u16* wl_l  = (u16*)alloc(4 * 65536 * sizeof(u16));
    u16* wr_h  = (u16*)alloc(4 * 65536 * sizeof(u16));
    u16* wr_l  = (u16*)alloc(4 * 65536 * sizeof(u16));
    u16* wsk_h = (u16*)alloc(4 * 65536 * sizeof(u16));
    u16* wsk_l = (u16*)alloc(4 * 65536 * sizeof(u16));
    u16* m1_h  = (u16*)alloc(131072 * sizeof(u16));
    u16* m1_l  = (u16*)alloc(131072 * sizeof(u16));
    u16* m2_h  = (u16*)alloc(131072 * sizeof(u16));
    u16* m2_l  = (u16*)alloc(131072 * sizeof(u16));
    // activation ping-pong (P1,P2 contiguous -> NN x 512 for MLP hidden)
    float* P0 = (float*)alloc((size_t)NN * HH * sizeof(float));
    float* P1 = (float*)alloc((size_t)NN * HH * sizeof(float));
    float* P2 = (float*)alloc((size_t)NN * HH * sizeof(float));

    // weight splits
    k_split<<<(65536 + 255) / 256, 256, 0, stream>>>(in_w, win_h, win_l, 65536);
    k_split<<<(262144 + 255) / 256, 256, 0, stream>>>(conv_wl, wl_h, wl_l, 262144);
    k_split<<<(262144 + 255) / 256, 256, 0, stream>>>(conv_wr, wr_h, wr_l, 262144);
    k_split<<<(262144 + 255) / 256, 256, 0, stream>>>(skip_w, wsk_h, wsk_l, 262144);
    k_split<<<(131072 + 255) / 256, 256, 0, stream>>>(mlp_w1, m1_h, m1_l, 131072);
    k_split<<<(131072 + 255) / 256, 256, 0, stream>>>(mlp_w2, m2_h, m2_l, 131072);

    // CSR build
    hipMemsetAsync(deg, 0, (size_t)NN * sizeof(int), stream);
    k_hist<<<(NE + 255) / 256, 256, 0, stream>>>(ei, deg);
    k_scan<<<1, 1024, 0, stream>>>(deg, rs, cur, idg);
    k_fill<<<(NE + 255) / 256, 256, 0, stream>>>(ei, cur, col);

    // input projection + ReLU
    launch_mfma<true, false>(NN, 256, 256, 256, 256, x, x,
                             win_h, win_l, win_h, win_l,
                             in_b, nullptr, nullptr, P0, stream);

    float* hcur = P0;
    float* hbuf = P1;
    float* conv = P2;
    for (int l = 0; l < NL; ++l) {
        k_aggregate<<<(NN + 3) / 4, 256, 0, stream>>>(hcur, rs, col, idg, hbuf);
        // conv = [agg | h] @ [wl | wr]^T + bl   (fused K=512 concat GEMM)
        launch_mfma<false, false>(NN, 512, 256, 256, 256, hbuf, hcur,
                                  wl_h + (size_t)l * 65536, wl_l + (size_t)l * 65536,
                                  wr_h + (size_t)l * 65536, wr_l + (size_t)l * 65536,
                                  conv_bl + l * HH, nullptr, nullptr, conv, stream);
        hipMemsetAsync(stats, 0, 2 * HH * sizeof(float), stream);
        k_bn_stats<<<1024, 256, 0, stream>>>(conv, stats);
        k_bn_finalize<<<1, 256, 0, stream>>>(stats, bn_g + l * HH, bn_b + l * HH, scsh);
        // h_next = relu(BN(conv)) + hcur @ skip_w^T + skip_b
        launch_mfma<false, true>(NN, 256, 256, 256, 256, hcur, hcur,
                                 wsk_h + (size_t)l * 65536, wsk_l + (size_t)l * 65536,
                                 wsk_h + (size_t)l * 65536, wsk_l + (size_t)l * 65536,
                                 skip_b + l * HH, conv, scsh, hbuf, stream);
        float* t = hcur; hcur = hbuf; hbuf = t;
    }
    // MLP: hidden = relu(h @ w1^T + b1)  (NN x 512, in P1:P2)
    float* mid = P1;
    launch_mfma<true, false>(NN, 256, 512, 256, 256, hcur, hcur,
                             m1_h, m1_l, m1_h, m1_l,
                             mlp_b1, nullptr, nullptr, mid, stream);
    // h = hidden @ w2^T + b2   (K=512 contiguous: A1 = mid+256, W1 = plane+256)
    launch_mfma<false, false>(NN, 512, 256, 512, 512, mid, mid + 256,
                              m2_h, m2_l, m2_h + 256, m2_l + 256,
                              mlp_b2, nullptr, nullptr, hcur, stream);

    k_out<<<(NN + 3) / 4, 256, 0, stream>>>(hcur, out_w, out_b, out);
}